// Round 7
// baseline (27.109 us; speedup 1.0000x reference)
//
#include <hip/hip_runtime.h>
#include <hip/hip_bf16.h>

#define LATENT 16
#define STATE  16
#define NPOS   (64 * 8192)
#define NTILES (NPOS / 16)        // 32768 tiles of 16 positions
#define TPW    4                  // tiles per wave

typedef __attribute__((ext_vector_type(4))) float f32x4;
typedef __attribute__((ext_vector_type(4))) unsigned int u32x4;
typedef __attribute__((ext_vector_type(8))) short bf16x8;  // 8 bf16 in 4 VGPRs

static __device__ __forceinline__ short f2bf(float f) {
    __hip_bfloat16 h = __float2bfloat16(f);
    return (short)__builtin_bit_cast(unsigned short, h);
}

// HW paired f32->bf16 RNE: dword = {bf16(hi) << 16 | bf16(lo)}.
// Non-volatile, no clobbers -> freely schedulable.
static __device__ __forceinline__ unsigned int cvtpk(float lo, float hi) {
    unsigned int r;
    asm("v_cvt_pk_bf16_f32 %0, %1, %2" : "=v"(r) : "v"(lo), "v"(hi));
    return r;
}

// ---------------- prep: pack W into MFMA B-fragment order ----------------
// ws layout: [0..15] f32 bias (const-term row); then 4608 ushort Wpack.
// Wpack[(c*64 + lane)*8 + jj] = bf16 W'[k = c*32 + (lane>>4)*8 + jj][col = lane&15]
// K order: k<256: x_I * x_J, I=k>>4, J=k&15 (off-diag weights halved);
//          k=256..271: linear x[k-256]; k=272..287: sin(x[k-272]).
__global__ __launch_bounds__(256) void prep_pack(const float* __restrict__ coef,
                                                 const float* __restrict__ mask,
                                                 float* __restrict__ wsf) {
    int id = blockIdx.x * 256 + threadIdx.x;
    if (id < 16) wsf[id] = coef[id] * mask[id];   // bias: ref row 0 (const)
    if (id >= 4608) return;
    int jj  = id & 7;
    int col = (id >> 3) & 15;
    int g   = (id >> 7) & 3;
    int c   = id >> 9;                    // 0..8
    int k   = c * 32 + g * 8 + jj;        // 0..287
    float scale = 1.0f;
    int row;
    if (k < 256) {
        int I = k >> 4, J = k & 15;
        int im = I < J ? I : J, jm = I < J ? J : I;
        int q = im * 16 - im * (im - 1) / 2 + (jm - im);  // comb_w_r index
        row = 17 + q;
        if (I != J) scale = 0.5f;
    } else if (k < 272) {
        row = 1 + (k - 256);
    } else {
        row = 153 + (k - 272);
    }
    float w = coef[row * STATE + col] * mask[row * STATE + col] * scale;
    ((ushort*)(wsf + 16))[id] = (ushort)f2bf(w);
}

// ---------------- main: theta-on-the-fly MFMA GEMM, no LDS, no allocas ----
// All register state is NAMED SSA (rule #20). bf16 conversion via
// v_cvt_pk_bf16_f32 (1 instr / 2 elems, HW RNE). Two accumulator chains
// (even/odd chunks) halve the serial MFMA dependency depth.
__global__ __launch_bounds__(256, 4) void sindy_mfma(const float* __restrict__ x,
                                                     const float* __restrict__ wsf,
                                                     float* __restrict__ out) {
    const int lane  = threadIdx.x & 63;
    const int wid   = threadIdx.x >> 6;
    const int g     = lane >> 4;          // K-slice group 0..3
    const int col   = lane & 15;          // A-row (position in tile) and D-col
    const bool hiJ  = (g & 1) != 0;       // J-half this lane multiplies
    const bool hiI  = (g >> 1) != 0;      // I parity this lane covers

    // B fragments: wave-wide resident, loaded once (9 x 16B per lane), NAMED
    const ushort* Wpack = (const ushort*)(wsf + 16);
    const bf16x8 b0 = *(const bf16x8*)(Wpack + (0 * 64 + lane) * 8);
    const bf16x8 b1 = *(const bf16x8*)(Wpack + (1 * 64 + lane) * 8);
    const bf16x8 b2 = *(const bf16x8*)(Wpack + (2 * 64 + lane) * 8);
    const bf16x8 b3 = *(const bf16x8*)(Wpack + (3 * 64 + lane) * 8);
    const bf16x8 b4 = *(const bf16x8*)(Wpack + (4 * 64 + lane) * 8);
    const bf16x8 b5 = *(const bf16x8*)(Wpack + (5 * 64 + lane) * 8);
    const bf16x8 b6 = *(const bf16x8*)(Wpack + (6 * 64 + lane) * 8);
    const bf16x8 b7 = *(const bf16x8*)(Wpack + (7 * 64 + lane) * 8);
    const bf16x8 b8 = *(const bf16x8*)(Wpack + (8 * 64 + lane) * 8);

    const float bias = wsf[col];
    const float4* x4 = (const float4*)x;

    const int wave_gid = blockIdx.x * 4 + wid;   // 8192 waves
    const int tile0 = wave_gid * TPW;
    const long base = (long)(tile0 * 16 + col) * 4;   // float4 index of my row

    auto do_tile = [&](int tile, float4 A, float4 B, float4 C, float4 D) {
        // xv: the J-half this lane multiplies (value selects, not addresses)
        const float xv0 = hiJ ? C.x : A.x;
        const float xv1 = hiJ ? C.y : A.y;
        const float xv2 = hiJ ? C.z : A.z;
        const float xv3 = hiJ ? C.w : A.w;
        const float xv4 = hiJ ? D.x : B.x;
        const float xv5 = hiJ ? D.y : B.y;
        const float xv6 = hiJ ? D.z : B.z;
        const float xv7 = hiJ ? D.w : B.w;
        // xi: element 2c + hiI
        const float xi0 = hiI ? A.y : A.x;
        const float xi1 = hiI ? A.w : A.z;
        const float xi2 = hiI ? B.y : B.x;
        const float xi3 = hiI ? B.w : B.z;
        const float xi4 = hiI ? C.y : C.x;
        const float xi5 = hiI ? C.w : C.z;
        const float xi6 = hiI ? D.y : D.x;
        const float xi7 = hiI ? D.w : D.z;

        f32x4 accE = {bias, bias, bias, bias};   // even chunks
        f32x4 accO = {0.f, 0.f, 0.f, 0.f};       // odd chunks

#define QUAD(BF, XI, ACC)                                                \
        {                                                                \
            u32x4 u;                                                     \
            u[0] = cvtpk((XI) * xv0, (XI) * xv1);                        \
            u[1] = cvtpk((XI) * xv2, (XI) * xv3);                        \
            u[2] = cvtpk((XI) * xv4, (XI) * xv5);                        \
            u[3] = cvtpk((XI) * xv6, (XI) * xv7);                        \
            ACC = __builtin_amdgcn_mfma_f32_16x16x32_bf16(                \
                      __builtin_bit_cast(bf16x8, u), BF, ACC, 0, 0, 0);  \
        }
        QUAD(b0, xi0, accE) QUAD(b1, xi1, accO)
        QUAD(b2, xi2, accE) QUAD(b3, xi3, accO)
        QUAD(b4, xi4, accE) QUAD(b5, xi5, accO)
        QUAD(b6, xi6, accE) QUAD(b7, xi7, accO)
#undef QUAD
        // chunk 8: g<2 -> linear xv; g>=2 -> sin(xv)
        {
            const bool us = (g >= 2);
            const float s0 = us ? __sinf(xv0) : xv0;
            const float s1 = us ? __sinf(xv1) : xv1;
            const float s2 = us ? __sinf(xv2) : xv2;
            const float s3 = us ? __sinf(xv3) : xv3;
            const float s4 = us ? __sinf(xv4) : xv4;
            const float s5 = us ? __sinf(xv5) : xv5;
            const float s6 = us ? __sinf(xv6) : xv6;
            const float s7 = us ? __sinf(xv7) : xv7;
            u32x4 u;
            u[0] = cvtpk(s0, s1);
            u[1] = cvtpk(s2, s3);
            u[2] = cvtpk(s4, s5);
            u[3] = cvtpk(s6, s7);
            accE = __builtin_amdgcn_mfma_f32_16x16x32_bf16(
                       __builtin_bit_cast(bf16x8, u), b8, accE, 0, 0, 0);
        }

        const f32x4 acc = accE + accO;

        // D: row = g*4 + r (position), col = state
        const long obase = (long)(tile * 16 + g * 4) * STATE + col;
        out[obase + 0 * STATE] = acc[0];
        out[obase + 1 * STATE] = acc[1];
        out[obase + 2 * STATE] = acc[2];
        out[obase + 3 * STATE] = acc[3];
    };

    float4 c0 = x4[base + 0], c1 = x4[base + 1],
           c2 = x4[base + 2], c3 = x4[base + 3];
    #pragma unroll
    for (int t = 0; t < TPW; ++t) {
        float4 n0 = c0, n1 = c1, n2 = c2, n3 = c3;
        if (t < TPW - 1) {                 // prefetch next tile's row
            const long nb = base + (long)(t + 1) * 64;
            n0 = x4[nb + 0]; n1 = x4[nb + 1];
            n2 = x4[nb + 2]; n3 = x4[nb + 3];
        }
        do_tile(tile0 + t, c0, c1, c2, c3);
        c0 = n0; c1 = n1; c2 = n2; c3 = n3;
    }
}

extern "C" void kernel_launch(void* const* d_in, const int* in_sizes, int n_in,
                              void* d_out, int out_size, void* d_ws, size_t ws_size,
                              hipStream_t stream) {
    const float* x    = (const float*)d_in[0];
    const float* coef = (const float*)d_in[1];
    const float* mask = (const float*)d_in[2];
    float*       wsf  = (float*)d_ws;     // 16 f32 bias + 4608 ushort Wpack
    float*       out  = (float*)d_out;

    prep_pack<<<18, 256, 0, stream>>>(coef, mask, wsf);
    sindy_mfma<<<NTILES / (4 * TPW), 256, 0, stream>>>(x, wsf, out);  // 2048 blocks
}

// Round 8
// 26.332 us; speedup vs baseline: 1.0295x; 1.0295x over previous
//
#include <hip/hip_runtime.h>
#include <hip/hip_bf16.h>

#define LATENT 16
#define STATE  16
#define NPOS   (64 * 8192)
#define NTILES (NPOS / 16)        // 32768 tiles of 16 positions
#define TPW    8                  // tiles per wave

typedef __attribute__((ext_vector_type(4))) float f32x4;
typedef __attribute__((ext_vector_type(8))) short bf16x8;  // 8 bf16 in 4 VGPRs

static __device__ __forceinline__ short f2bf(float f) {
    __hip_bfloat16 h = __float2bfloat16(f);
    return (short)__builtin_bit_cast(unsigned short, h);
}

// ---------------- prep: pack W into MFMA B-fragment order ----------------
// ws layout: [0..15] f32 bias (const-term row); then 4608 ushort Wpack.
// Wpack[(c*64 + lane)*8 + jj] = bf16 W'[k = c*32 + (lane>>4)*8 + jj][col = lane&15]
// K order: k<256: x_I * x_J, I=k>>4, J=k&15 (off-diag weights halved);
//          k=256..271: linear x[k-256]; k=272..287: sin(x[k-272]).
__global__ __launch_bounds__(256) void prep_pack(const float* __restrict__ coef,
                                                 const float* __restrict__ mask,
                                                 float* __restrict__ wsf) {
    int id = blockIdx.x * 256 + threadIdx.x;
    if (id < 16) wsf[id] = coef[id] * mask[id];   // bias: ref row 0 (const)
    if (id >= 4608) return;
    int jj  = id & 7;
    int col = (id >> 3) & 15;
    int g   = (id >> 7) & 3;
    int c   = id >> 9;                    // 0..8
    int k   = c * 32 + g * 8 + jj;        // 0..287
    float scale = 1.0f;
    int row;
    if (k < 256) {
        int I = k >> 4, J = k & 15;
        int im = I < J ? I : J, jm = I < J ? J : I;
        int q = im * 16 - im * (im - 1) / 2 + (jm - im);  // comb_w_r index
        row = 17 + q;
        if (I != J) scale = 0.5f;
    } else if (k < 272) {
        row = 1 + (k - 256);
    } else {
        row = 153 + (k - 272);
    }
    float w = coef[row * STATE + col] * mask[row * STATE + col] * scale;
    ((ushort*)(wsf + 16))[id] = (ushort)f2bf(w);
}

// ---------------- main: theta-on-the-fly MFMA GEMM, no LDS, no allocas ----
// R6 tile body unchanged (best measured). New: TPW=8 + depth-2 register
// prefetch pipeline — loads for tile t+2 issue before computing tile t,
// giving ~2 tile-bodies (~520+ cyc) of latency cover per load.
__global__ __launch_bounds__(256, 4) void sindy_mfma(const float* __restrict__ x,
                                                     const float* __restrict__ wsf,
                                                     float* __restrict__ out) {
    const int lane  = threadIdx.x & 63;
    const int wid   = threadIdx.x >> 6;
    const int g     = lane >> 4;          // K-slice group 0..3
    const int col   = lane & 15;          // A-row (position in tile) and D-col
    const bool hiJ  = (g & 1) != 0;       // J-half this lane multiplies
    const bool hiI  = (g >> 1) != 0;      // I parity this lane covers

    // B fragments: wave-wide resident, loaded once (9 x 16B per lane), NAMED
    const ushort* Wpack = (const ushort*)(wsf + 16);
    const bf16x8 b0 = *(const bf16x8*)(Wpack + (0 * 64 + lane) * 8);
    const bf16x8 b1 = *(const bf16x8*)(Wpack + (1 * 64 + lane) * 8);
    const bf16x8 b2 = *(const bf16x8*)(Wpack + (2 * 64 + lane) * 8);
    const bf16x8 b3 = *(const bf16x8*)(Wpack + (3 * 64 + lane) * 8);
    const bf16x8 b4 = *(const bf16x8*)(Wpack + (4 * 64 + lane) * 8);
    const bf16x8 b5 = *(const bf16x8*)(Wpack + (5 * 64 + lane) * 8);
    const bf16x8 b6 = *(const bf16x8*)(Wpack + (6 * 64 + lane) * 8);
    const bf16x8 b7 = *(const bf16x8*)(Wpack + (7 * 64 + lane) * 8);
    const bf16x8 b8 = *(const bf16x8*)(Wpack + (8 * 64 + lane) * 8);

    const float bias = wsf[col];
    const float4* x4 = (const float4*)x;

    const int wave_gid = blockIdx.x * 4 + wid;   // 4096 waves
    const int tile0 = wave_gid * TPW;
    const long base = (long)(tile0 * 16 + col) * 4;   // float4 index of my row

    // per-tile body: all operands are by-value SSA (rule #20: no arrays)
    auto do_tile = [&](int tile, float4 A, float4 B, float4 C, float4 D) {
        // xv: the J-half this lane multiplies (value selects, not addresses)
        const float xv0 = hiJ ? C.x : A.x;
        const float xv1 = hiJ ? C.y : A.y;
        const float xv2 = hiJ ? C.z : A.z;
        const float xv3 = hiJ ? C.w : A.w;
        const float xv4 = hiJ ? D.x : B.x;
        const float xv5 = hiJ ? D.y : B.y;
        const float xv6 = hiJ ? D.z : B.z;
        const float xv7 = hiJ ? D.w : B.w;
        // xi: element 2c + hiI
        const float xi0 = hiI ? A.y : A.x;
        const float xi1 = hiI ? A.w : A.z;
        const float xi2 = hiI ? B.y : B.x;
        const float xi3 = hiI ? B.w : B.z;
        const float xi4 = hiI ? C.y : C.x;
        const float xi5 = hiI ? C.w : C.z;
        const float xi6 = hiI ? D.y : D.x;
        const float xi7 = hiI ? D.w : D.z;

        f32x4 acc = {bias, bias, bias, bias};

#define QUAD(BF, XI)                                                     \
        {                                                                \
            bf16x8 af;                                                   \
            af[0] = f2bf((XI) * xv0); af[1] = f2bf((XI) * xv1);          \
            af[2] = f2bf((XI) * xv2); af[3] = f2bf((XI) * xv3);          \
            af[4] = f2bf((XI) * xv4); af[5] = f2bf((XI) * xv5);          \
            af[6] = f2bf((XI) * xv6); af[7] = f2bf((XI) * xv7);          \
            acc = __builtin_amdgcn_mfma_f32_16x16x32_bf16(af, BF, acc, 0, 0, 0); \
        }
        QUAD(b0, xi0) QUAD(b1, xi1) QUAD(b2, xi2) QUAD(b3, xi3)
        QUAD(b4, xi4) QUAD(b5, xi5) QUAD(b6, xi6) QUAD(b7, xi7)
#undef QUAD
        // chunk 8: g<2 -> linear xv; g>=2 -> sin(xv)
        {
            const bool us = (g >= 2);
            bf16x8 af;
            af[0] = f2bf(us ? __sinf(xv0) : xv0);
            af[1] = f2bf(us ? __sinf(xv1) : xv1);
            af[2] = f2bf(us ? __sinf(xv2) : xv2);
            af[3] = f2bf(us ? __sinf(xv3) : xv3);
            af[4] = f2bf(us ? __sinf(xv4) : xv4);
            af[5] = f2bf(us ? __sinf(xv5) : xv5);
            af[6] = f2bf(us ? __sinf(xv6) : xv6);
            af[7] = f2bf(us ? __sinf(xv7) : xv7);
            acc = __builtin_amdgcn_mfma_f32_16x16x32_bf16(af, b8, acc, 0, 0, 0);
        }

        // D: row = g*4 + r (position), col = state
        const long obase = (long)(tile * 16 + g * 4) * STATE + col;
        out[obase + 0 * STATE] = acc[0];
        out[obase + 1 * STATE] = acc[1];
        out[obase + 2 * STATE] = acc[2];
        out[obase + 3 * STATE] = acc[3];
    };

    // depth-2 software pipeline over TPW tiles, named-register rotation
    float4 c0 = x4[base + 0],  c1 = x4[base + 1],
           c2 = x4[base + 2],  c3 = x4[base + 3];        // tile t
    float4 p0 = x4[base + 64], p1 = x4[base + 65],
           p2 = x4[base + 66], p3 = x4[base + 67];       // tile t+1

    #pragma unroll
    for (int t = 0; t < TPW; ++t) {
        float4 q0 = p0, q1 = p1, q2 = p2, q3 = p3;       // tile t+2
        if (t + 2 < TPW) {
            const long nb = base + (long)(t + 2) * 64;
            q0 = x4[nb + 0]; q1 = x4[nb + 1];
            q2 = x4[nb + 2]; q3 = x4[nb + 3];
        }
        do_tile(tile0 + t, c0, c1, c2, c3);
        c0 = p0; c1 = p1; c2 = p2; c3 = p3;
        p0 = q0; p1 = q1; p2 = q2; p3 = q3;
    }
}

extern "C" void kernel_launch(void* const* d_in, const int* in_sizes, int n_in,
                              void* d_out, int out_size, void* d_ws, size_t ws_size,
                              hipStream_t stream) {
    const float* x    = (const float*)d_in[0];
    const float* coef = (const float*)d_in[1];
    const float* mask = (const float*)d_in[2];
    float*       wsf  = (float*)d_ws;     // 16 f32 bias + 4608 ushort Wpack
    float*       out  = (float*)d_out;

    prep_pack<<<18, 256, 0, stream>>>(coef, mask, wsf);
    sindy_mfma<<<NTILES / (4 * TPW), 256, 0, stream>>>(x, wsf, out);  // 1024 blocks
}

// Round 9
// 26.173 us; speedup vs baseline: 1.0358x; 1.0061x over previous
//
#include <hip/hip_runtime.h>
#include <hip/hip_bf16.h>

#define LATENT 16
#define STATE  16
#define NPOS   (64 * 8192)
#define NTILES (NPOS / 16)        // 32768 tiles of 16 positions
#define TPW    8                  // tiles per wave

typedef __attribute__((ext_vector_type(4))) float f32x4;
typedef __attribute__((ext_vector_type(8))) short bf16x8;  // 8 bf16 in 4 VGPRs

static __device__ __forceinline__ short f2bf(float f) {
    __hip_bfloat16 h = __float2bfloat16(f);
    return (short)__builtin_bit_cast(unsigned short, h);
}

// ---------------- prep: pack W into MFMA fragment order ----------------
// ws layout: [0..15] f32 bias (const-term row); then 4608 ushort Wpack.
// Wpack[(c*64 + lane)*8 + jj] = bf16 W'[k = c*32 + (lane>>4)*8 + jj][lane&15]
// Same packing serves as the MFMA **A** operand (A[row=state][k]) because
// A and B share the lane->(dim16,k) mapping on gfx950 16x16x32.
// K order: k<256: x_I * x_J, I=k>>4, J=k&15 (off-diag weights halved);
//          k=256..271: linear x[k-256]; k=272..287: sin(x[k-272]).
__global__ __launch_bounds__(256) void prep_pack(const float* __restrict__ coef,
                                                 const float* __restrict__ mask,
                                                 float* __restrict__ wsf) {
    int id = blockIdx.x * 256 + threadIdx.x;
    if (id < 16) wsf[id] = coef[id] * mask[id];   // bias: ref row 0 (const)
    if (id >= 4608) return;
    int jj  = id & 7;
    int col = (id >> 3) & 15;
    int g   = (id >> 7) & 3;
    int c   = id >> 9;                    // 0..8
    int k   = c * 32 + g * 8 + jj;        // 0..287
    float scale = 1.0f;
    int row;
    if (k < 256) {
        int I = k >> 4, J = k & 15;
        int im = I < J ? I : J, jm = I < J ? J : I;
        int q = im * 16 - im * (im - 1) / 2 + (jm - im);  // comb_w_r index
        row = 17 + q;
        if (I != J) scale = 0.5f;
    } else if (k < 272) {
        row = 1 + (k - 256);
    } else {
        row = 153 + (k - 272);
    }
    float w = coef[row * STATE + col] * mask[row * STATE + col] * scale;
    ((ushort*)(wsf + 16))[id] = (ushort)f2bf(w);
}

// ---------------- main: theta-on-the-fly MFMA GEMM, swapped operands ----
// acc = mfma(Wfrag, theta_frag, acc) computes (theta*W)^T per tile:
// D col = lane&15 = POSITION, D row = g*4+r = STATE. Each lane's 4 acc
// values are 4 consecutive floats of one output row -> ONE dwordx4 store
// per tile (was 4 scattered dword stores). Per-lane math unchanged.
__global__ __launch_bounds__(256, 4) void sindy_mfma(const float* __restrict__ x,
                                                     const float* __restrict__ wsf,
                                                     float* __restrict__ out) {
    const int lane  = threadIdx.x & 63;
    const int wid   = threadIdx.x >> 6;
    const int g     = lane >> 4;          // K-slice group 0..3
    const int col   = lane & 15;          // position-in-tile (theta B-col)
    const bool hiJ  = (g & 1) != 0;       // J-half this lane multiplies
    const bool hiI  = (g >> 1) != 0;      // I parity this lane covers

    // W fragments (A operand): wave-resident, loaded once, NAMED (rule #20)
    const ushort* Wpack = (const ushort*)(wsf + 16);
    const bf16x8 b0 = *(const bf16x8*)(Wpack + (0 * 64 + lane) * 8);
    const bf16x8 b1 = *(const bf16x8*)(Wpack + (1 * 64 + lane) * 8);
    const bf16x8 b2 = *(const bf16x8*)(Wpack + (2 * 64 + lane) * 8);
    const bf16x8 b3 = *(const bf16x8*)(Wpack + (3 * 64 + lane) * 8);
    const bf16x8 b4 = *(const bf16x8*)(Wpack + (4 * 64 + lane) * 8);
    const bf16x8 b5 = *(const bf16x8*)(Wpack + (5 * 64 + lane) * 8);
    const bf16x8 b6 = *(const bf16x8*)(Wpack + (6 * 64 + lane) * 8);
    const bf16x8 b7 = *(const bf16x8*)(Wpack + (7 * 64 + lane) * 8);
    const bf16x8 b8 = *(const bf16x8*)(Wpack + (8 * 64 + lane) * 8);

    // bias per STATE: acc reg r holds state g*4+r
    const float4 bias4 = *(const float4*)(wsf + g * 4);

    const float4* x4 = (const float4*)x;
    const int wave_gid = blockIdx.x * 4 + wid;   // 4096 waves
    const int tile0 = wave_gid * TPW;
    const long base = (long)(tile0 * 16 + col) * 4;   // float4 idx of my row

    auto do_tile = [&](int tile, float4 A, float4 B, float4 C, float4 D) {
        // xv: the J-half this lane multiplies (value selects, not addresses)
        const float xv0 = hiJ ? C.x : A.x;
        const float xv1 = hiJ ? C.y : A.y;
        const float xv2 = hiJ ? C.z : A.z;
        const float xv3 = hiJ ? C.w : A.w;
        const float xv4 = hiJ ? D.x : B.x;
        const float xv5 = hiJ ? D.y : B.y;
        const float xv6 = hiJ ? D.z : B.z;
        const float xv7 = hiJ ? D.w : B.w;
        // xi: element 2c + hiI
        const float xi0 = hiI ? A.y : A.x;
        const float xi1 = hiI ? A.w : A.z;
        const float xi2 = hiI ? B.y : B.x;
        const float xi3 = hiI ? B.w : B.z;
        const float xi4 = hiI ? C.y : C.x;
        const float xi5 = hiI ? C.w : C.z;
        const float xi6 = hiI ? D.y : D.x;
        const float xi7 = hiI ? D.w : D.z;

        f32x4 acc = {bias4.x, bias4.y, bias4.z, bias4.w};

#define QUAD(BF, XI)                                                     \
        {                                                                \
            bf16x8 af;                                                   \
            af[0] = f2bf((XI) * xv0); af[1] = f2bf((XI) * xv1);          \
            af[2] = f2bf((XI) * xv2); af[3] = f2bf((XI) * xv3);          \
            af[4] = f2bf((XI) * xv4); af[5] = f2bf((XI) * xv5);          \
            af[6] = f2bf((XI) * xv6); af[7] = f2bf((XI) * xv7);          \
            acc = __builtin_amdgcn_mfma_f32_16x16x32_bf16(BF, af, acc, 0, 0, 0); \
        }
        QUAD(b0, xi0) QUAD(b1, xi1) QUAD(b2, xi2) QUAD(b3, xi3)
        QUAD(b4, xi4) QUAD(b5, xi5) QUAD(b6, xi6) QUAD(b7, xi7)
#undef QUAD
        // chunk 8: g<2 -> linear xv; g>=2 -> sin(xv)
        {
            const bool us = (g >= 2);
            bf16x8 af;
            af[0] = f2bf(us ? __sinf(xv0) : xv0);
            af[1] = f2bf(us ? __sinf(xv1) : xv1);
            af[2] = f2bf(us ? __sinf(xv2) : xv2);
            af[3] = f2bf(us ? __sinf(xv3) : xv3);
            af[4] = f2bf(us ? __sinf(xv4) : xv4);
            af[5] = f2bf(us ? __sinf(xv5) : xv5);
            af[6] = f2bf(us ? __sinf(xv6) : xv6);
            af[7] = f2bf(us ? __sinf(xv7) : xv7);
            acc = __builtin_amdgcn_mfma_f32_16x16x32_bf16(b8, af, acc, 0, 0, 0);
        }

        // D^T: lane writes states g*4..g*4+3 of position col -> one dwordx4
        float4 res;
        res.x = acc[0]; res.y = acc[1]; res.z = acc[2]; res.w = acc[3];
        *(float4*)(out + (long)(tile * 16 + col) * STATE + g * 4) = res;
    };

    // depth-1 register prefetch over TPW tiles (named rotation, no arrays)
    float4 c0 = x4[base + 0], c1 = x4[base + 1],
           c2 = x4[base + 2], c3 = x4[base + 3];
    #pragma unroll
    for (int t = 0; t < TPW; ++t) {
        float4 n0 = c0, n1 = c1, n2 = c2, n3 = c3;
        if (t + 1 < TPW) {
            const long nb = base + (long)(t + 1) * 64;
            n0 = x4[nb + 0]; n1 = x4[nb + 1];
            n2 = x4[nb + 2]; n3 = x4[nb + 3];
        }
        do_tile(tile0 + t, c0, c1, c2, c3);
        c0 = n0; c1 = n1; c2 = n2; c3 = n3;
    }
}

extern "C" void kernel_launch(void* const* d_in, const int* in_sizes, int n_in,
                              void* d_out, int out_size, void* d_ws, size_t ws_size,
                              hipStream_t stream) {
    const float* x    = (const float*)d_in[0];
    const float* coef = (const float*)d_in[1];
    const float* mask = (const float*)d_in[2];
    float*       wsf  = (float*)d_ws;     // 16 f32 bias + 4608 ushort Wpack
    float*       out  = (float*)d_out;

    prep_pack<<<18, 256, 0, stream>>>(coef, mask, wsf);
    sindy_mfma<<<NTILES / (4 * TPW), 256, 0, stream>>>(x, wsf, out);  // 1024 blocks
}